// Round 2
// baseline (133.360 us; speedup 1.0000x reference)
//
#include <hip/hip_runtime.h>

// Problem constants (fixed by the reference file).
#define DIN  4096
#define NG   4096          // NUM_GATES = DOUT/3
#define BS   4096
#define ROWS_PER_BLOCK 16
#define GATES_PER_THREAD 4
#define BLOCK_THREADS 256

typedef float v4f __attribute__((ext_vector_type(4)));  // native vec for nontemporal store

// out[b,g] = w0*x[b,(3g+1)&4095] + w1*x[b,(3g+2)&4095] + w2*x[b,(3g+3)&4095] + w3
// where (w0..w3) = softmax(wgts[g,0,0..3]).
// (Reference's signals[:, :, ::3] selects only row 0 of M = [1,0,0,0,0] -> out = s[...,0].)
// Each thread: 4 consecutive gates -> window x[12t .. 12t+12] (mod 4096),
// loaded as three 16B-aligned float4 + one scalar. The &4095 wrap never splits
// an aligned float4 (4096 % 4 == 0).
__global__ __launch_bounds__(BLOCK_THREADS) void fredkin_s0_kernel(
    const float* __restrict__ x,
    const float* __restrict__ wgts,
    float* __restrict__ out)
{
    const int tg = blockIdx.x * BLOCK_THREADS + threadIdx.x;  // 0..1023 gate-group
    const int g0 = tg * GATES_PER_THREAD;

    // Softmax of wgts[g,0,:] for the 4 gates this thread owns.
    // wgts row-0 of gate g is at float offset g*12 -> byte offset 48g, 16B aligned.
    float4 w[GATES_PER_THREAD];
#pragma unroll
    for (int j = 0; j < GATES_PER_THREAD; ++j) {
        float4 r = *reinterpret_cast<const float4*>(wgts + (size_t)(g0 + j) * 12);
        float m  = fmaxf(fmaxf(r.x, r.y), fmaxf(r.z, r.w));
        float e0 = __expf(r.x - m);
        float e1 = __expf(r.y - m);
        float e2 = __expf(r.z - m);
        float e3 = __expf(r.w - m);
        float inv = 1.0f / (e0 + e1 + e2 + e3);
        w[j] = make_float4(e0 * inv, e1 * inv, e2 * inv, e3 * inv);
    }

    // x window indices (multiples of 4, wrapped mod DIN independently).
    const int base = (tg * 12) & (DIN - 1);
    const int i0 = base;
    const int i1 = (base + 4)  & (DIN - 1);
    const int i2 = (base + 8)  & (DIN - 1);
    const int i3 = (base + 12) & (DIN - 1);

    const int brow = blockIdx.y * ROWS_PER_BLOCK;
    const float* xr   = x   + (size_t)brow * DIN;
    float*       orow = out + (size_t)brow * NG + g0;

#pragma unroll 2
    for (int r = 0; r < ROWS_PER_BLOCK; ++r) {
        float4 f0 = *reinterpret_cast<const float4*>(xr + i0); // e0..e3
        float4 f1 = *reinterpret_cast<const float4*>(xr + i1); // e4..e7
        float4 f2 = *reinterpret_cast<const float4*>(xr + i2); // e8..e11
        float  e12 = xr[i3];                                   // e12

        v4f o;
        // gate g0+0: e1,e2,e3
        o.x = fmaf(w[0].x, f0.y, fmaf(w[0].y, f0.z, fmaf(w[0].z, f0.w, w[0].w)));
        // gate g0+1: e4,e5,e6
        o.y = fmaf(w[1].x, f1.x, fmaf(w[1].y, f1.y, fmaf(w[1].z, f1.z, w[1].w)));
        // gate g0+2: e7,e8,e9
        o.z = fmaf(w[2].x, f1.w, fmaf(w[2].y, f2.x, fmaf(w[2].z, f2.y, w[2].w)));
        // gate g0+3: e10,e11,e12
        o.w = fmaf(w[3].x, f2.z, fmaf(w[3].y, f2.w, fmaf(w[3].z, e12, w[3].w)));

        __builtin_nontemporal_store(o, reinterpret_cast<v4f*>(orow));

        xr   += DIN;
        orow += NG;
    }
}

extern "C" void kernel_launch(void* const* d_in, const int* in_sizes, int n_in,
                              void* d_out, int out_size, void* d_ws, size_t ws_size,
                              hipStream_t stream) {
    const float* x    = (const float*)d_in[0];   // (BS, DIN) fp32
    const float* wgts = (const float*)d_in[1];   // (NG, 3, 4) fp32
    // d_in[2] (connections) is deterministic: (3g+1+j) % DIN — computed inline.
    float* out = (float*)d_out;                  // (BS, NG) fp32

    dim3 grid(NG / (BLOCK_THREADS * GATES_PER_THREAD),  // 4
              BS / ROWS_PER_BLOCK);                     // 256
    fredkin_s0_kernel<<<grid, dim3(BLOCK_THREADS), 0, stream>>>(x, wgts, out);
}